// Round 6
// baseline (43386.847 us; speedup 1.0000x reference)
//
#include <hip/hip_runtime.h>
#include <hip/hip_bf16.h>
#include <math.h>

#define DEV static __device__ __forceinline__

DEV float bf2f(const __hip_bfloat16 v) { return __bfloat162float(v); }

DEV float mishf(float x) {
    // x * tanh(softplus(x)); sp >= 0; tanh via exp(-2sp) rational — NaN-free
    float sp = fmaxf(x, 0.0f) + log1pf(expf(-fabsf(x)));
    float t = expf(-2.0f * sp);          // in (0,1]
    return x * (1.0f - t) / (1.0f + t);  // denom in [1,2]
}

#define N_T 32
struct Tab {
    const void* src[N_T];
    long long   dstoff[N_T];
    int         n[N_T];
};

// ---------------- per-array dtype detection ----------------
__global__ __launch_bounds__(256) void k_detect(Tab t, int* __restrict__ flags) {
    int i = blockIdx.x;
    int n = t.n[i];
    int m = n < 16384 ? n : 16384;
    const unsigned short* p = (const unsigned short*)t.src[i];
    __shared__ int sInf, sExt, sZero;
    if (threadIdx.x == 0) { sInf = 0; sExt = 0; sZero = 0; }
    __syncthreads();
    int cInf = 0, cExt = 0, cZero = 0;
    for (int j = threadIdx.x; j < m; j += 256) {
        unsigned short h = p[j];
        if ((h & 0x7F80) == 0x7F80) cInf++;
        if ((j & 1) == 0) {
            if (h == 0) cZero++;
            else { int e = (h >> 7) & 0xFF; if (e < 56 || e > 184) cExt++; }
        }
    }
    if (cInf)  atomicAdd(&sInf, cInf);
    if (cExt)  atomicAdd(&sExt, cExt);
    if (cZero) atomicAdd(&sZero, cZero);
    __syncthreads();
    if (threadIdx.x == 0) {
        int nEven = (m + 1) >> 1;
        flags[i] = (sInf > 0 || sExt > 0 || (nEven > 0 && sZero == nEven)) ? 2 : 0;
    }
}

__global__ void k_flag_final(Tab t, int* __restrict__ flags, int xi) {
    if (threadIdx.x == 0 && blockIdx.x == 0) {
        int xf = (flags[xi] == 2) ? 1 : 0;
        for (int i = 0; i < N_T; ++i) {
            int f;
            if (flags[i] == 2)       f = 1;
            else if (t.n[i] >= 256)  f = 0;
            else                     f = xf;
            flags[i] = f;            // 1 = f32, 0 = bf16
        }
    }
}

__global__ __launch_bounds__(256) void k_convert(
        Tab t, float* __restrict__ ws, const int* __restrict__ flags) {
    long long idx = (long long)blockIdx.x * 256 + threadIdx.x;
    long long off = 0;
    #pragma unroll 1
    for (int i = 0; i < N_T; ++i) {
        long long ni = t.n[i];
        if (idx < off + ni) {
            long long j = idx - off;
            float v = flags[i] ? ((const float*)t.src[i])[j]
                               : bf2f(((const __hip_bfloat16*)t.src[i])[j]);
            ws[t.dstoff[i] + j] = v;
            return;
        }
        off += ni;
    }
}

// ---------------- dynamic per-sample conv (k=4, pad=1) + mish ----------------
__global__ __launch_bounds__(256) void k_dynconv_mish(
        const float* __restrict__ x, const float* __restrict__ w,
        float* __restrict__ out) {
    const int HO = 255, WO = 255, H = 256, W = 256;
    int idx = blockIdx.x * 256 + threadIdx.x;
    int total = 4 * 32 * HO * WO;
    if (idx >= total) return;
    int xo = idx % WO; int t = idx / WO;
    int yo = t % HO;  t /= HO;
    int co = t & 31;  int b = t >> 5;
    const float* wp = w + (((b << 5) + co) << 4);
    const float* xp = x + b * H * W;
    float acc = 0.0f;
    #pragma unroll
    for (int ky = 0; ky < 4; ++ky) {
        int iy = yo + ky - 1;
        if ((unsigned)iy >= (unsigned)H) continue;
        const float* row = xp + iy * W;
        #pragma unroll
        for (int kx = 0; kx < 4; ++kx) {
            int ix = xo + kx - 1;
            if ((unsigned)ix < (unsigned)W)
                acc = fmaf(row[ix], wp[ky * 4 + kx], acc);
        }
    }
    out[idx] = mishf(acc);
}

// ---------------- generic conv (two-source implicit concat) + bias + mish ----
template<int K>
__global__ __launch_bounds__(256) void k_conv_mish(
        const float* __restrict__ s0, int C0,
        const float* __restrict__ s1, int C1,
        const float* __restrict__ wgt,
        const float* __restrict__ bias,
        float* __restrict__ out,
        int Hin, int Win, int Hout, int Wout,
        int Co, int pad, int total) {
    int idx = blockIdx.x * 256 + threadIdx.x;
    if (idx >= total) return;
    int xo = idx % Wout; int t = idx / Wout;
    int yo = t % Hout;  t /= Hout;
    int co = t % Co;    int b = t / Co;
    int Cin = C0 + C1;
    float acc = bias[co];
    const float* wbase = wgt + (size_t)co * Cin * (K * K);
    for (int ci = 0; ci < C0; ++ci) {
        const float* sp = s0 + (size_t)(b * C0 + ci) * Hin * Win;
        const float* wp = wbase + ci * (K * K);
        #pragma unroll
        for (int ky = 0; ky < K; ++ky) {
            int iy = yo + ky - pad;
            if ((unsigned)iy >= (unsigned)Hin) continue;
            const float* row = sp + (size_t)iy * Win;
            #pragma unroll
            for (int kx = 0; kx < K; ++kx) {
                int ix = xo + kx - pad;
                if ((unsigned)ix < (unsigned)Win)
                    acc = fmaf(row[ix], wp[ky * K + kx], acc);
            }
        }
    }
    for (int ci = 0; ci < C1; ++ci) {
        const float* sp = s1 + (size_t)(b * C1 + ci) * Hin * Win;
        const float* wp = wbase + (C0 + ci) * (K * K);
        #pragma unroll
        for (int ky = 0; ky < K; ++ky) {
            int iy = yo + ky - pad;
            if ((unsigned)iy >= (unsigned)Hin) continue;
            const float* row = sp + (size_t)iy * Win;
            #pragma unroll
            for (int kx = 0; kx < K; ++kx) {
                int ix = xo + kx - pad;
                if ((unsigned)ix < (unsigned)Win)
                    acc = fmaf(row[ix], wp[ky * K + kx], acc);
            }
        }
    }
    out[idx] = mishf(acc);
}

// ---------------- 2x2 maxpool stride 2 ----------------
__global__ __launch_bounds__(256) void k_maxpool(
        const float* __restrict__ in, float* __restrict__ out,
        int Hin, int Win, int total) {
    int idx = blockIdx.x * 256 + threadIdx.x;
    if (idx >= total) return;
    int Wo = Win >> 1, Ho = Hin >> 1;
    int xo = idx % Wo; int t = idx / Wo;
    int yo = t % Ho;   t /= Ho;
    const float* p = in + ((size_t)t * Hin + 2 * yo) * Win + 2 * xo;
    out[idx] = fmaxf(fmaxf(p[0], p[1]), fmaxf(p[Win], p[Win + 1]));
}

// ---------------- batchnorm (batch stats) ----------------
__global__ __launch_bounds__(256) void k_bn_reduce(
        const float* __restrict__ in, float* __restrict__ stats) {
    __shared__ float ls[4], ls2[4];
    int c = blockIdx.x;
    int tid = threadIdx.x;
    float s = 0.f, s2 = 0.f;
    for (int i = tid; i < 4096; i += 256) {
        int b = i >> 10, r = i & 1023;
        float v = in[((size_t)(b * 512 + c) << 10) + r];
        s += v; s2 += v * v;
    }
    #pragma unroll
    for (int off = 32; off; off >>= 1) {
        s  += __shfl_down(s, off, 64);
        s2 += __shfl_down(s2, off, 64);
    }
    if ((tid & 63) == 0) { ls[tid >> 6] = s; ls2[tid >> 6] = s2; }
    __syncthreads();
    if (tid == 0) {
        s  = ls[0] + ls[1] + ls[2] + ls[3];
        s2 = ls2[0] + ls2[1] + ls2[2] + ls2[3];
        float mean = s * (1.f / 4096.f);
        float var  = fmaxf(s2 * (1.f / 4096.f) - mean * mean, 0.f);
        stats[c]       = mean;
        stats[512 + c] = rsqrtf(var + 1e-5f);
    }
}

__global__ __launch_bounds__(256) void k_bn_apply(
        float* __restrict__ data, const float* __restrict__ stats,
        const float* __restrict__ g, const float* __restrict__ be, int total) {
    int idx = blockIdx.x * 256 + threadIdx.x;
    if (idx >= total) return;
    int c = (idx >> 10) & 511;
    float v = data[idx];
    data[idx] = g[c] * (v - stats[c]) * stats[512 + c] + be[c];
}

// ------------- bilinear x2 upsample, align_corners=True, ONE batch -----------
__global__ __launch_bounds__(256) void k_up2b(
        const float* __restrict__ in, float* __restrict__ out,
        int C, int H, int W, int total) {
    int idx = blockIdx.x * 256 + threadIdx.x;
    if (idx >= total) return;
    int Wo = W * 2, Ho = H * 2;
    int xo = idx % Wo; int t = idx / Wo;
    int yo = t % Ho;   int c = t / Ho;
    float scy = (float)(H - 1) / (float)(Ho - 1);
    float scx = (float)(W - 1) / (float)(Wo - 1);
    float sy = yo * scy, sx = xo * scx;
    int y0 = (int)sy; int y1 = min(y0 + 1, H - 1); float fy = sy - (float)y0;
    int x0 = (int)sx; int x1 = min(x0 + 1, W - 1); float fx = sx - (float)x0;
    const float* p = in + (size_t)c * H * W;
    float a  = p[y0 * W + x0] * (1.f - fx) + p[y0 * W + x1] * fx;
    float b2 = p[y1 * W + x0] * (1.f - fx) + p[y1 * W + x1] * fx;
    out[idx] = a * (1.f - fy) + b2 * fy;
}

// ---------------- final 1x1 conv, 32 -> 1, F32 out (reference dtype) --------
__global__ __launch_bounds__(256) void k_final1x1(
        const float* __restrict__ in, const float* __restrict__ wl,
        const float* __restrict__ bl, float* __restrict__ out) {
    int idx = blockIdx.x * 256 + threadIdx.x;
    if (idx >= 4 * 256 * 256) return;
    int pix = idx & 65535;
    int b = idx >> 16;
    float acc = bl[0];
    #pragma unroll
    for (int ci = 0; ci < 32; ++ci)
        acc = fmaf(in[((size_t)(b * 32 + ci) << 16) + pix], wl[ci], acc);
    out[idx] = acc;
}

static inline int nblk(long long n) { return (int)((n + 255) / 256); }

extern "C" void kernel_launch(void* const* d_in, const int* in_sizes, int n_in,
                              void* d_out, int out_size, void* d_ws, size_t ws_size,
                              hipStream_t stream) {
    static const int EXP_SZ[N_T] = {
        262144, 2048, 16384, 32, 36864, 128, 147456, 128,
        294912, 256, 589824, 256, 1179648, 512, 2359296, 512,
        512, 512, 1769472, 256, 589824, 256, 442368, 128,
        147456, 128, 46080, 32, 9216, 32, 32, 1 };
    int o = -1;
    for (int s = 0; s + N_T <= n_in; ++s) {
        bool ok = true;
        for (int j = 0; j < N_T; ++j)
            if (in_sizes[s + j] != EXP_SZ[j]) { ok = false; break; }
        if (ok) { o = s; break; }
    }
    if (o < 0) return;

    float* ws = (float*)d_ws;
    Tab tab;
    float* fp[N_T];
    long long off = 0;
    for (int i = 0; i < N_T; ++i) {
        tab.src[i] = d_in[o + i];
        tab.n[i] = in_sizes[o + i];
        tab.dstoff[i] = off;
        fp[i] = ws + off;
        off += in_sizes[o + i];
    }
    const long long PARF = 7897088;
    if (off > PARF) return;
    float* C1 = ws + PARF;                      // 8,388,608
    float* C2 = C1 + 8388608;                   // 8,388,608
    float* C3 = C2 + 8388608;                   // 4,194,304
    float* P  = C3 + 4194304;                   // 8,388,608
    float* Q  = P  + 8388608;                   // 8,388,608
    float* ST = Q  + 8388608;                   // 1,024
    int* FLAGS = (int*)(ST + 1024);             // 32 ints
    const size_t NEED = ((size_t)(PARF + 8388608ll*3 + 4194304 + 1024) + 64) * 4;
    if (ws_size < NEED) return;

    const float* xf  = fp[0];  const float* wf  = fp[1];
    const float* d1w = fp[2],  *d1b = fp[3];
    const float* w2a = fp[4],  *b2a = fp[5],  *w2b = fp[6],  *b2b = fp[7];
    const float* w3a = fp[8],  *b3a = fp[9],  *w3b = fp[10], *b3b = fp[11];
    const float* w4a = fp[12], *b4a = fp[13], *w4b = fp[14], *b4b = fp[15];
    const float* g4  = fp[16], *be4 = fp[17];
    const float* u3a = fp[18], *ub3a = fp[19], *u3b = fp[20], *ub3b = fp[21];
    const float* u2a = fp[22], *ub2a = fp[23], *u2b = fp[24], *ub2b = fp[25];
    const float* u1a = fp[26], *ub1a = fp[27], *u1b = fp[28], *ub1b = fp[29];
    const float* wl  = fp[30], *bl = fp[31];
    float* outp = (float*)d_out;                // reference output dtype = f32

    dim3 blk(256);
    long long n;

    // 0. dtype detect + convert to f32
    k_detect<<<N_T, blk, 0, stream>>>(tab, FLAGS);
    k_flag_final<<<1, 64, 0, stream>>>(tab, FLAGS, 0);
    k_convert<<<nblk(off), blk, 0, stream>>>(tab, ws, FLAGS);

    // ---- encoder ----
    n = 4ll * 32 * 255 * 255;
    k_dynconv_mish<<<nblk(n), blk, 0, stream>>>(xf, wf, P);
    n = 4ll * 32 * 256 * 256;
    k_conv_mish<4><<<nblk(n), blk, 0, stream>>>(P, 32, nullptr, 0, d1w, d1b, C1,
                                                255, 255, 256, 256, 32, 2, (int)n);
    n = 4ll * 32 * 128 * 128;
    k_maxpool<<<nblk(n), blk, 0, stream>>>(C1, Q, 256, 256, (int)n);
    n = 4ll * 128 * 128 * 128;
    k_conv_mish<3><<<nblk(n), blk, 0, stream>>>(Q, 32, nullptr, 0, w2a, b2a, P,
                                                128, 128, 128, 128, 128, 1, (int)n);
    k_conv_mish<3><<<nblk(n), blk, 0, stream>>>(P, 128, nullptr, 0, w2b, b2b, C2,
                                                128, 128, 128, 128, 128, 1, (int)n);
    n = 4ll * 128 * 64 * 64;
    k_maxpool<<<nblk(n), blk, 0, stream>>>(C2, Q, 128, 128, (int)n);
    n = 4ll * 256 * 64 * 64;
    k_conv_mish<3><<<nblk(n), blk, 0, stream>>>(Q, 128, nullptr, 0, w3a, b3a, P,
                                                64, 64, 64, 64, 256, 1, (int)n);
    k_conv_mish<3><<<nblk(n), blk, 0, stream>>>(P, 256, nullptr, 0, w3b, b3b, C3,
                                                64, 64, 64, 64, 256, 1, (int)n);
    n = 4ll * 256 * 32 * 32;
    k_maxpool<<<nblk(n), blk, 0, stream>>>(C3, Q, 64, 64, (int)n);
    n = 4ll * 512 * 32 * 32;
    k_conv_mish<3><<<nblk(n), blk, 0, stream>>>(Q, 256, nullptr, 0, w4a, b4a, P,
                                                32, 32, 32, 32, 512, 1, (int)n);
    k_conv_mish<3><<<nblk(n), blk, 0, stream>>>(P, 512, nullptr, 0, w4b, b4b, Q,
                                                32, 32, 32, 32, 512, 1, (int)n);
    k_bn_reduce<<<512, blk, 0, stream>>>(Q, ST);
    k_bn_apply<<<nblk(n), blk, 0, stream>>>(Q, ST, g4, be4, (int)n);

    // ---- decoder, materialized per-batch upsample ----
    float* U3 = P + 4194304;                    // tail of P region (disjoint)
    for (int b = 0; b < 4; ++b) {
        k_up2b<<<nblk(2097152), blk, 0, stream>>>(Q + (size_t)b * 524288, U3,
                                                  512, 32, 32, 2097152);
        k_conv_mish<3><<<nblk(1048576), blk, 0, stream>>>(
            U3, 512, C3 + (size_t)b * 1048576, 256, u3a, ub3a,
            P + (size_t)b * 1048576, 64, 64, 64, 64, 256, 1, 1048576);
    }
    n = 4ll * 256 * 64 * 64;
    k_conv_mish<3><<<nblk(n), blk, 0, stream>>>(P, 256, nullptr, 0, u3b, ub3b, Q,
                                                64, 64, 64, 64, 256, 1, (int)n);

    float* U2 = C3;
    for (int b = 0; b < 4; ++b) {
        k_up2b<<<nblk(4194304), blk, 0, stream>>>(Q + (size_t)b * 1048576, U2,
                                                  256, 64, 64, 4194304);
        k_conv_mish<3><<<nblk(2097152), blk, 0, stream>>>(
            U2, 256, C2 + (size_t)b * 2097152, 128, u2a, ub2a,
            P + (size_t)b * 2097152, 128, 128, 128, 128, 128, 1, 2097152);
    }
    n = 4ll * 128 * 128 * 128;
    k_conv_mish<3><<<nblk(n), blk, 0, stream>>>(P, 128, nullptr, 0, u2b, ub2b, Q,
                                                128, 128, 128, 128, 128, 1, (int)n);

    float* U1 = C2;
    for (int b = 0; b < 4; ++b) {
        k_up2b<<<nblk(8388608), blk, 0, stream>>>(Q + (size_t)b * 2097152, U1,
                                                  128, 128, 128, 8388608);
        k_conv_mish<3><<<nblk(2097152), blk, 0, stream>>>(
            U1, 128, C1 + (size_t)b * 2097152, 32, u1a, ub1a,
            P + (size_t)b * 2097152, 256, 256, 256, 256, 32, 1, 2097152);
    }
    n = 4ll * 32 * 256 * 256;
    k_conv_mish<3><<<nblk(n), blk, 0, stream>>>(P, 32, nullptr, 0, u1b, ub1b, Q,
                                                256, 256, 256, 256, 32, 1, (int)n);

    // final 1x1 -> f32 out
    n = 4ll * 256 * 256;
    k_final1x1<<<nblk(n), blk, 0, stream>>>(Q, wl, bl, outp);
}

// Round 7
// 7150.116 us; speedup vs baseline: 6.0680x; 6.0680x over previous
//
#include <hip/hip_runtime.h>
#include <hip/hip_bf16.h>
#include <math.h>

#define DEV static __device__ __forceinline__

DEV float bf2f(const __hip_bfloat16 v) { return __bfloat162float(v); }

DEV float mishf(float x) {
    float sp = fmaxf(x, 0.0f) + log1pf(expf(-fabsf(x)));
    float t = expf(-2.0f * sp);
    return x * (1.0f - t) / (1.0f + t);
}

#define N_T 32
struct Tab {
    const void* src[N_T];
    long long   dstoff[N_T];
    int         n[N_T];
};

// ---------------- per-array dtype detection ----------------
__global__ __launch_bounds__(256) void k_detect(Tab t, int* __restrict__ flags) {
    int i = blockIdx.x;
    int n = t.n[i];
    int m = n < 16384 ? n : 16384;
    const unsigned short* p = (const unsigned short*)t.src[i];
    __shared__ int sInf, sExt, sZero;
    if (threadIdx.x == 0) { sInf = 0; sExt = 0; sZero = 0; }
    __syncthreads();
    int cInf = 0, cExt = 0, cZero = 0;
    for (int j = threadIdx.x; j < m; j += 256) {
        unsigned short h = p[j];
        if ((h & 0x7F80) == 0x7F80) cInf++;
        if ((j & 1) == 0) {
            if (h == 0) cZero++;
            else { int e = (h >> 7) & 0xFF; if (e < 56 || e > 184) cExt++; }
        }
    }
    if (cInf)  atomicAdd(&sInf, cInf);
    if (cExt)  atomicAdd(&sExt, cExt);
    if (cZero) atomicAdd(&sZero, cZero);
    __syncthreads();
    if (threadIdx.x == 0) {
        int nEven = (m + 1) >> 1;
        flags[i] = (sInf > 0 || sExt > 0 || (nEven > 0 && sZero == nEven)) ? 2 : 0;
    }
}

__global__ void k_flag_final(Tab t, int* __restrict__ flags, int xi) {
    if (threadIdx.x == 0 && blockIdx.x == 0) {
        int xf = (flags[xi] == 2) ? 1 : 0;
        for (int i = 0; i < N_T; ++i) {
            int f;
            if (flags[i] == 2)       f = 1;
            else if (t.n[i] >= 256)  f = 0;
            else                     f = xf;
            flags[i] = f;
        }
    }
}

__global__ __launch_bounds__(256) void k_convert(
        Tab t, float* __restrict__ ws, const int* __restrict__ flags) {
    long long idx = (long long)blockIdx.x * 256 + threadIdx.x;
    long long off = 0;
    #pragma unroll 1
    for (int i = 0; i < N_T; ++i) {
        long long ni = t.n[i];
        if (idx < off + ni) {
            long long j = idx - off;
            float v = flags[i] ? ((const float*)t.src[i])[j]
                               : bf2f(((const __hip_bfloat16*)t.src[i])[j]);
            ws[t.dstoff[i] + j] = v;
            return;
        }
        off += ni;
    }
}

// ---------------- dynamic per-sample conv (k=4, pad=1) + mish (tiny) --------
__global__ __launch_bounds__(256) void k_dynconv_mish(
        const float* __restrict__ x, const float* __restrict__ w,
        float* __restrict__ out) {
    const int HO = 255, WO = 255, H = 256, W = 256;
    int idx = blockIdx.x * 256 + threadIdx.x;
    int total = 4 * 32 * HO * WO;
    if (idx >= total) return;
    int xo = idx % WO; int t = idx / WO;
    int yo = t % HO;  t /= HO;
    int co = t & 31;  int b = t >> 5;
    const float* wp = w + (((b << 5) + co) << 4);
    const float* xp = x + b * H * W;
    float acc = 0.0f;
    #pragma unroll
    for (int ky = 0; ky < 4; ++ky) {
        int iy = yo + ky - 1;
        if ((unsigned)iy >= (unsigned)H) continue;
        const float* row = xp + iy * W;
        #pragma unroll
        for (int kx = 0; kx < 4; ++kx) {
            int ix = xo + kx - 1;
            if ((unsigned)ix < (unsigned)W)
                acc = fmaf(row[ix], wp[ky * 4 + kx], acc);
        }
    }
    out[idx] = mishf(acc);
}

// ============== register-tiled conv: 4 co x TX xs per thread =================
// Weights indexed from blockIdx.y only -> wave-uniform -> s_load (SMEM pipe).
// AL: input rows are float4-alignable (Win % 4 == 0).
template<int K, int TX, bool AL>
DEV void conv_accum(const float* __restrict__ src, int C, int Hin, int Win,
                    const float* __restrict__ wgt, int Cin, int coff,
                    int cobase, int yo, int x0, float acc[4][TX]) {
    constexpr int PAD  = (K == 3) ? 1 : 2;
    constexpr int KK   = K * K;
    constexpr int SPAN = TX + K - 1;
    const float* sp = src;
    #pragma unroll 1
    for (int ci = 0; ci < C; ++ci) {
        #pragma unroll
        for (int ky = 0; ky < K; ++ky) {
            // uniform weight loads (scalar pipe)
            float wk[4][K];
            #pragma unroll
            for (int c = 0; c < 4; ++c)
                #pragma unroll
                for (int kx = 0; kx < K; ++kx)
                    wk[c][kx] = wgt[(size_t)((cobase + c) * Cin + (coff + ci)) * KK
                                    + ky * K + kx];
            int iy = yo + ky - PAD;
            float a[SPAN];
            if ((unsigned)iy < (unsigned)Hin) {
                const float* rowp = sp + (size_t)iy * Win;
                if (AL) {
                    #pragma unroll
                    for (int v = 0; v < TX / 4; ++v) {
                        float4 f = *(const float4*)(rowp + x0 + 4 * v);
                        a[PAD + 4 * v + 0] = f.x; a[PAD + 4 * v + 1] = f.y;
                        a[PAD + 4 * v + 2] = f.z; a[PAD + 4 * v + 3] = f.w;
                    }
                    #pragma unroll
                    for (int j = 0; j < PAD; ++j) {       // left halo
                        int col = x0 + j - PAD;
                        a[j] = (col >= 0) ? rowp[col] : 0.f;
                    }
                    #pragma unroll
                    for (int j = PAD + TX; j < SPAN; ++j) { // right halo
                        int col = x0 + j - PAD;
                        a[j] = (col < Win) ? rowp[col] : 0.f;
                    }
                } else {
                    #pragma unroll
                    for (int j = 0; j < SPAN; ++j) {
                        int col = x0 + j - PAD;
                        a[j] = ((unsigned)col < (unsigned)Win) ? rowp[col] : 0.f;
                    }
                }
            } else {
                #pragma unroll
                for (int j = 0; j < SPAN; ++j) a[j] = 0.f;
            }
            #pragma unroll
            for (int c = 0; c < 4; ++c)
                #pragma unroll
                for (int kx = 0; kx < K; ++kx) {
                    float w = wk[c][kx];
                    #pragma unroll
                    for (int xx = 0; xx < TX; ++xx)
                        acc[c][xx] = fmaf(a[kx + xx], w, acc[c][xx]);
                }
        }
        sp += (size_t)Hin * Win;
    }
}

template<int K, int TX, bool AL>
__global__ __launch_bounds__(256) void k_conv_tile(
        const float* __restrict__ s0, int C0,
        const float* __restrict__ s1, int C1,
        const float* __restrict__ wgt, const float* __restrict__ bias,
        float* __restrict__ out,
        int Hin, int Win, int Hout, int Wout) {
    int tpr  = Wout / TX;              // threads per output row
    int tid  = threadIdx.x;
    int xg   = tid % tpr;
    int yo   = blockIdx.x * (256 / tpr) + tid / tpr;
    int x0   = xg * TX;
    int cobase = blockIdx.y * 4;
    int b    = blockIdx.z;
    int Cin  = C0 + C1;
    int Co   = gridDim.y * 4;

    float acc[4][TX];
    #pragma unroll
    for (int c = 0; c < 4; ++c) {
        float bv = bias[cobase + c];
        #pragma unroll
        for (int xx = 0; xx < TX; ++xx) acc[c][xx] = bv;
    }
    conv_accum<K, TX, AL>(s0 + (size_t)b * C0 * Hin * Win, C0, Hin, Win,
                          wgt, Cin, 0, cobase, yo, x0, acc);
    if (C1)
        conv_accum<K, TX, AL>(s1 + (size_t)b * C1 * Hin * Win, C1, Hin, Win,
                              wgt, Cin, C0, cobase, yo, x0, acc);
    #pragma unroll
    for (int c = 0; c < 4; ++c) {
        float* op = out + (((size_t)(b * Co + cobase + c)) * Hout + yo) * Wout + x0;
        #pragma unroll
        for (int v = 0; v < TX / 4; ++v) {
            float4 r;
            r.x = mishf(acc[c][4 * v + 0]);
            r.y = mishf(acc[c][4 * v + 1]);
            r.z = mishf(acc[c][4 * v + 2]);
            r.w = mishf(acc[c][4 * v + 3]);
            *(float4*)(op + 4 * v) = r;
        }
    }
}

// ---------------- 2x2 maxpool stride 2 ----------------
__global__ __launch_bounds__(256) void k_maxpool(
        const float* __restrict__ in, float* __restrict__ out,
        int Hin, int Win, int total) {
    int idx = blockIdx.x * 256 + threadIdx.x;
    if (idx >= total) return;
    int Wo = Win >> 1, Ho = Hin >> 1;
    int xo = idx % Wo; int t = idx / Wo;
    int yo = t % Ho;   t /= Ho;
    const float* p = in + ((size_t)t * Hin + 2 * yo) * Win + 2 * xo;
    out[idx] = fmaxf(fmaxf(p[0], p[1]), fmaxf(p[Win], p[Win + 1]));
}

// ---------------- batchnorm (batch stats) ----------------
__global__ __launch_bounds__(256) void k_bn_reduce(
        const float* __restrict__ in, float* __restrict__ stats) {
    __shared__ float ls[4], ls2[4];
    int c = blockIdx.x;
    int tid = threadIdx.x;
    float s = 0.f, s2 = 0.f;
    for (int i = tid; i < 4096; i += 256) {
        int b = i >> 10, r = i & 1023;
        float v = in[((size_t)(b * 512 + c) << 10) + r];
        s += v; s2 += v * v;
    }
    #pragma unroll
    for (int off = 32; off; off >>= 1) {
        s  += __shfl_down(s, off, 64);
        s2 += __shfl_down(s2, off, 64);
    }
    if ((tid & 63) == 0) { ls[tid >> 6] = s; ls2[tid >> 6] = s2; }
    __syncthreads();
    if (tid == 0) {
        s  = ls[0] + ls[1] + ls[2] + ls[3];
        s2 = ls2[0] + ls2[1] + ls2[2] + ls2[3];
        float mean = s * (1.f / 4096.f);
        float var  = fmaxf(s2 * (1.f / 4096.f) - mean * mean, 0.f);
        stats[c]       = mean;
        stats[512 + c] = rsqrtf(var + 1e-5f);
    }
}

__global__ __launch_bounds__(256) void k_bn_apply(
        float* __restrict__ data, const float* __restrict__ stats,
        const float* __restrict__ g, const float* __restrict__ be, int total) {
    int idx = blockIdx.x * 256 + threadIdx.x;
    if (idx >= total) return;
    int c = (idx >> 10) & 511;
    float v = data[idx];
    data[idx] = g[c] * (v - stats[c]) * stats[512 + c] + be[c];
}

// ------------- bilinear x2 upsample, align_corners=True ----------------------
__global__ __launch_bounds__(256) void k_up2b(
        const float* __restrict__ in, float* __restrict__ out,
        int C, int H, int W, int total) {
    int idx = blockIdx.x * 256 + threadIdx.x;
    if (idx >= total) return;
    int Wo = W * 2, Ho = H * 2;
    int xo = idx % Wo; int t = idx / Wo;
    int yo = t % Ho;   int c = t / Ho;
    float scy = (float)(H - 1) / (float)(Ho - 1);
    float scx = (float)(W - 1) / (float)(Wo - 1);
    float sy = yo * scy, sx = xo * scx;
    int y0 = (int)sy; int y1 = min(y0 + 1, H - 1); float fy = sy - (float)y0;
    int x0 = (int)sx; int x1 = min(x0 + 1, W - 1); float fx = sx - (float)x0;
    const float* p = in + (size_t)c * H * W;
    float a  = p[y0 * W + x0] * (1.f - fx) + p[y0 * W + x1] * fx;
    float b2 = p[y1 * W + x0] * (1.f - fx) + p[y1 * W + x1] * fx;
    out[idx] = a * (1.f - fy) + b2 * fy;
}

// ---------------- final 1x1 conv, 32 -> 1, f32 out ----------------
__global__ __launch_bounds__(256) void k_final1x1(
        const float* __restrict__ in, const float* __restrict__ wl,
        const float* __restrict__ bl, float* __restrict__ out) {
    int idx = blockIdx.x * 256 + threadIdx.x;
    if (idx >= 4 * 256 * 256) return;
    int pix = idx & 65535;
    int b = idx >> 16;
    float acc = bl[0];
    #pragma unroll
    for (int ci = 0; ci < 32; ++ci)
        acc = fmaf(in[((size_t)(b * 32 + ci) << 16) + pix], wl[ci], acc);
    out[idx] = acc;
}

static inline int nblk(long long n) { return (int)((n + 255) / 256); }

extern "C" void kernel_launch(void* const* d_in, const int* in_sizes, int n_in,
                              void* d_out, int out_size, void* d_ws, size_t ws_size,
                              hipStream_t stream) {
    static const int EXP_SZ[N_T] = {
        262144, 2048, 16384, 32, 36864, 128, 147456, 128,
        294912, 256, 589824, 256, 1179648, 512, 2359296, 512,
        512, 512, 1769472, 256, 589824, 256, 442368, 128,
        147456, 128, 46080, 32, 9216, 32, 32, 1 };
    int o = -1;
    for (int s = 0; s + N_T <= n_in; ++s) {
        bool ok = true;
        for (int j = 0; j < N_T; ++j)
            if (in_sizes[s + j] != EXP_SZ[j]) { ok = false; break; }
        if (ok) { o = s; break; }
    }
    if (o < 0) return;

    float* ws = (float*)d_ws;
    Tab tab;
    float* fp[N_T];
    long long off = 0;
    for (int i = 0; i < N_T; ++i) {
        tab.src[i] = d_in[o + i];
        tab.n[i] = in_sizes[o + i];
        tab.dstoff[i] = off;
        fp[i] = ws + off;
        off += in_sizes[o + i];
    }
    const long long PARF = 7897088;
    if (off > PARF) return;
    float* C1 = ws + PARF;                      // 8,388,608
    float* C2 = C1 + 8388608;                   // 8,388,608
    float* C3 = C2 + 8388608;                   // 4,194,304
    float* P  = C3 + 4194304;                   // 8,388,608
    float* Q  = P  + 8388608;                   // 8,388,608
    float* ST = Q  + 8388608;                   // 1,024
    int* FLAGS = (int*)(ST + 1024);
    const size_t NEED = ((size_t)(PARF + 8388608ll*3 + 4194304 + 1024) + 64) * 4;
    if (ws_size < NEED) return;

    const float* xf  = fp[0];  const float* wf  = fp[1];
    const float* d1w = fp[2],  *d1b = fp[3];
    const float* w2a = fp[4],  *b2a = fp[5],  *w2b = fp[6],  *b2b = fp[7];
    const float* w3a = fp[8],  *b3a = fp[9],  *w3b = fp[10], *b3b = fp[11];
    const float* w4a = fp[12], *b4a = fp[13], *w4b = fp[14], *b4b = fp[15];
    const float* g4  = fp[16], *be4 = fp[17];
    const float* u3a = fp[18], *ub3a = fp[19], *u3b = fp[20], *ub3b = fp[21];
    const float* u2a = fp[22], *ub2a = fp[23], *u2b = fp[24], *ub2b = fp[25];
    const float* u1a = fp[26], *ub1a = fp[27], *u1b = fp[28], *ub1b = fp[29];
    const float* wl  = fp[30], *bl = fp[31];
    float* outp = (float*)d_out;

    dim3 blk(256);
    long long n;

    k_detect<<<N_T, blk, 0, stream>>>(tab, FLAGS);
    k_flag_final<<<1, 64, 0, stream>>>(tab, FLAGS, 0);
    k_convert<<<nblk(off), blk, 0, stream>>>(tab, ws, FLAGS);

    // ---- encoder ----
    n = 4ll * 32 * 255 * 255;
    k_dynconv_mish<<<nblk(n), blk, 0, stream>>>(xf, wf, P);
    // d1: k=4 pad=2, (4,32,255,255) -> C1 (4,32,256,256).  grid(32, 8, 4)
    k_conv_tile<4, 8, false><<<dim3(32, 8, 4), blk, 0, stream>>>(
        P, 32, nullptr, 0, d1w, d1b, C1, 255, 255, 256, 256);
    n = 4ll * 32 * 128 * 128;
    k_maxpool<<<nblk(n), blk, 0, stream>>>(C1, Q, 256, 256, (int)n);
    // c2a: 32->128 @128².  tpr=16, rows=16, gx=8
    k_conv_tile<3, 8, true><<<dim3(8, 32, 4), blk, 0, stream>>>(
        Q, 32, nullptr, 0, w2a, b2a, P, 128, 128, 128, 128);
    k_conv_tile<3, 8, true><<<dim3(8, 32, 4), blk, 0, stream>>>(
        P, 128, nullptr, 0, w2b, b2b, C2, 128, 128, 128, 128);
    n = 4ll * 128 * 64 * 64;
    k_maxpool<<<nblk(n), blk, 0, stream>>>(C2, Q, 128, 128, (int)n);
    // c3a: 128->256 @64².  tpr=8, rows=32, gx=2
    k_conv_tile<3, 8, true><<<dim3(2, 64, 4), blk, 0, stream>>>(
        Q, 128, nullptr, 0, w3a, b3a, P, 64, 64, 64, 64);
    k_conv_tile<3, 8, true><<<dim3(2, 64, 4), blk, 0, stream>>>(
        P, 256, nullptr, 0, w3b, b3b, C3, 64, 64, 64, 64);
    n = 4ll * 256 * 32 * 32;
    k_maxpool<<<nblk(n), blk, 0, stream>>>(C3, Q, 64, 64, (int)n);
    // c4a: 256->512 @32².  TX=4: tpr=8, rows=32, gx=1
    k_conv_tile<3, 4, true><<<dim3(1, 128, 4), blk, 0, stream>>>(
        Q, 256, nullptr, 0, w4a, b4a, P, 32, 32, 32, 32);
    k_conv_tile<3, 4, true><<<dim3(1, 128, 4), blk, 0, stream>>>(
        P, 512, nullptr, 0, w4b, b4b, Q, 32, 32, 32, 32);
    n = 4ll * 512 * 32 * 32;
    k_bn_reduce<<<512, blk, 0, stream>>>(Q, ST);
    k_bn_apply<<<nblk(n), blk, 0, stream>>>(Q, ST, g4, be4, (int)n);

    // ---- decoder ----
    // stage 3 (full batch): up2(Q:(4,512,32,32)) -> P (4,512,64,64)
    n = 4ll * 512 * 64 * 64;
    k_up2b<<<nblk(n), blk, 0, stream>>>(Q, P, 2048, 32, 32, (int)n);
    // u3a: [P:512 | C3:256] -> Q (4,256,64,64)
    k_conv_tile<3, 8, true><<<dim3(2, 64, 4), blk, 0, stream>>>(
        P, 512, C3, 256, u3a, ub3a, Q, 64, 64, 64, 64);
    // u3b: Q -> P
    k_conv_tile<3, 8, true><<<dim3(2, 64, 4), blk, 0, stream>>>(
        Q, 256, nullptr, 0, u3b, ub3b, P, 64, 64, 64, 64);

    // stage 2 (per batch): up2(P slice) -> U2(=C3 dead), conv -> Q slice
    float* U2 = C3;
    for (int b = 0; b < 4; ++b) {
        k_up2b<<<nblk(4194304), blk, 0, stream>>>(P + (size_t)b * 1048576, U2,
                                                  256, 64, 64, 4194304);
        k_conv_tile<3, 8, true><<<dim3(8, 32, 1), blk, 0, stream>>>(
            U2, 256, C2 + (size_t)b * 2097152, 128, u2a, ub2a,
            Q + (size_t)b * 2097152, 128, 128, 128, 128);
    }
    // u2b: Q -> P (4,128,128,128)
    k_conv_tile<3, 8, true><<<dim3(8, 32, 4), blk, 0, stream>>>(
        Q, 128, nullptr, 0, u2b, ub2b, P, 128, 128, 128, 128);

    // stage 1 (per batch): up2(P slice) -> U1(=C2 dead), conv -> Q slice
    float* U1 = C2;
    for (int b = 0; b < 4; ++b) {
        k_up2b<<<nblk(8388608), blk, 0, stream>>>(P + (size_t)b * 2097152, U1,
                                                  128, 128, 128, 8388608);
        k_conv_tile<3, 8, true><<<dim3(32, 8, 1), blk, 0, stream>>>(
            U1, 128, C1 + (size_t)b * 2097152, 32, u1a, ub1a,
            Q + (size_t)b * 2097152, 256, 256, 256, 256);
    }
    // u1b: Q -> P (4,32,256,256)
    k_conv_tile<3, 8, true><<<dim3(32, 8, 4), blk, 0, stream>>>(
        Q, 32, nullptr, 0, u1b, ub1b, P, 256, 256, 256, 256);

    // final 1x1 -> f32 out
    n = 4ll * 256 * 256;
    k_final1x1<<<nblk(n), blk, 0, stream>>>(P, wl, bl, outp);
}

// Round 8
// 4114.497 us; speedup vs baseline: 10.5449x; 1.7378x over previous
//
#include <hip/hip_runtime.h>
#include <hip/hip_bf16.h>
#include <math.h>

#define DEV static __device__ __forceinline__

typedef __attribute__((ext_vector_type(8))) short short8;
typedef __attribute__((ext_vector_type(4))) float floatx4;

DEV float bf2f(const __hip_bfloat16 v) { return __bfloat162float(v); }

DEV unsigned short f2bf(float v) {   // RNE f32 -> bf16 bits
    unsigned int b = __float_as_uint(v);
    unsigned int r = (b + 0x7FFFu + ((b >> 16) & 1u)) >> 16;
    return (unsigned short)r;
}

DEV float mishf(float x) {
    float sp = fmaxf(x, 0.0f) + log1pf(expf(-fabsf(x)));
    float t = expf(-2.0f * sp);
    return x * (1.0f - t) / (1.0f + t);
}

#define N_T 32
struct Tab {
    const void* src[N_T];
    long long   dstoff[N_T];
    int         n[N_T];
    int         isw[N_T];   // 1 = weight -> bf16 WB region, else f32 PF region
};

// ---------------- per-array dtype detection ----------------
__global__ __launch_bounds__(256) void k_detect(Tab t, int* __restrict__ flags) {
    int i = blockIdx.x;
    int n = t.n[i];
    int m = n < 16384 ? n : 16384;
    const unsigned short* p = (const unsigned short*)t.src[i];
    __shared__ int sInf, sExt, sZero;
    if (threadIdx.x == 0) { sInf = 0; sExt = 0; sZero = 0; }
    __syncthreads();
    int cInf = 0, cExt = 0, cZero = 0;
    for (int j = threadIdx.x; j < m; j += 256) {
        unsigned short h = p[j];
        if ((h & 0x7F80) == 0x7F80) cInf++;
        if ((j & 1) == 0) {
            if (h == 0) cZero++;
            else { int e = (h >> 7) & 0xFF; if (e < 56 || e > 184) cExt++; }
        }
    }
    if (cInf)  atomicAdd(&sInf, cInf);
    if (cExt)  atomicAdd(&sExt, cExt);
    if (cZero) atomicAdd(&sZero, cZero);
    __syncthreads();
    if (threadIdx.x == 0) {
        int nEven = (m + 1) >> 1;
        flags[i] = (sInf > 0 || sExt > 0 || (nEven > 0 && sZero == nEven)) ? 2 : 0;
    }
}

__global__ void k_flag_final(Tab t, int* __restrict__ flags, int xi) {
    if (threadIdx.x == 0 && blockIdx.x == 0) {
        int xf = (flags[xi] == 2) ? 1 : 0;
        for (int i = 0; i < N_T; ++i) {
            int f;
            if (flags[i] == 2)       f = 1;
            else if (t.n[i] >= 256)  f = 0;
            else                     f = xf;
            flags[i] = f;            // 1 = f32, 0 = bf16
        }
    }
}

// convert inputs: weights -> bf16 (WB), everything else -> f32 (PF)
__global__ __launch_bounds__(256) void k_convert(
        Tab t, float* __restrict__ pf, unsigned short* __restrict__ wb,
        const int* __restrict__ flags) {
    long long idx = (long long)blockIdx.x * 256 + threadIdx.x;
    long long off = 0;
    #pragma unroll 1
    for (int i = 0; i < N_T; ++i) {
        long long ni = t.n[i];
        if (idx < off + ni) {
            long long j = idx - off;
            float v = flags[i] ? ((const float*)t.src[i])[j]
                               : bf2f(((const __hip_bfloat16*)t.src[i])[j]);
            if (t.isw[i]) wb[t.dstoff[i] + j] = f2bf(v);
            else          pf[t.dstoff[i] + j] = v;
            return;
        }
        off += ni;
    }
}

// ---------------- dynamic per-sample conv (k=4, pad=1) + mish ---------------
__global__ __launch_bounds__(256) void k_dynconv_mish(
        const float* __restrict__ x, const float* __restrict__ w,
        float* __restrict__ out) {
    const int HO = 255, WO = 255, H = 256, W = 256;
    int idx = blockIdx.x * 256 + threadIdx.x;
    int total = 4 * 32 * HO * WO;
    if (idx >= total) return;
    int xo = idx % WO; int t = idx / WO;
    int yo = t % HO;  t /= HO;
    int co = t & 31;  int b = t >> 5;
    const float* wp = w + (((b << 5) + co) << 4);
    const float* xp = x + b * H * W;
    float acc = 0.0f;
    #pragma unroll
    for (int ky = 0; ky < 4; ++ky) {
        int iy = yo + ky - 1;
        if ((unsigned)iy >= (unsigned)H) continue;
        const float* row = xp + iy * W;
        #pragma unroll
        for (int kx = 0; kx < 4; ++kx) {
            int ix = xo + kx - 1;
            if ((unsigned)ix < (unsigned)W)
                acc = fmaf(row[ix], wp[ky * 4 + kx], acc);
        }
    }
    out[idx] = mishf(acc);
}

// =============== implicit-GEMM MFMA conv (bf16 in, f32 acc) ==================
// A = weights (Co x Cin*KS*KS) bf16 row-major; B = im2col(activations).
// Block: MB co x 64 pixels; 4 waves, each = MB co x 16 pixels.
// Activations f32 in memory; converted to bf16 when staged to LDS.
template<int KS, int MB>
__global__ __launch_bounds__(256) void k_conv_mfma(
        const float* __restrict__ s0, int C0,
        const float* __restrict__ s1, int C1,
        const unsigned short* __restrict__ wb,
        const float* __restrict__ bias,
        float* __restrict__ out,
        int Hin, int Win, int lgW, int lgHW, int Co, int ktot) {
    constexpr int PAD = (KS == 3) ? 1 : 2;
    constexpr int KK  = KS * KS;
    __shared__ __align__(16) short ldsA[MB * 32];
    __shared__ __align__(16) short ldsB[64 * 32];

    const int tid  = threadIdx.x;
    const int lane = tid & 63, wv = tid >> 6;
    const int m = lane & 15, quad = lane >> 4;
    const int W = 1 << lgW, HW = 1 << lgHW;

    const int pixbase = blockIdx.x * 64;
    const int cobase  = blockIdx.y * MB;

    // B-staging invariants: thread handles k-row kr, pixel group grp (8 px)
    const int kr = tid & 31, grp = tid >> 5;
    const int Pg  = pixbase + grp * 8;
    const int bB  = Pg >> lgHW;
    const int pg  = Pg & (HW - 1);
    const int yB  = pg >> lgW;
    const int x0B = pg & (W - 1);

    // A-staging invariants (tid < MB*4): 8 bf16 per thread per k-step
    const int co_r = tid >> 2, segi = tid & 3;
    const unsigned short* wA = wb + (size_t)(cobase + co_r) * ktot + segi * 8;

    floatx4 acc[MB / 16];
    #pragma unroll
    for (int q = 0; q < MB / 16; ++q) acc[q] = (floatx4){0.f, 0.f, 0.f, 0.f};

    const int nk = ktot >> 5;
    for (int ks = 0; ks < nk; ++ks) {
        // ---- stage A tile (MB x 32 bf16)
        if (MB == 64 || tid < 128) {
            uint4 a4 = *(const uint4*)wA;
            *(uint4*)&ldsA[co_r * 32 + segi * 8] = a4;
        }
        // ---- stage B tile (64 pix x 32 k, transposed in LDS)
        {
            int k  = (ks << 5) + kr;
            int ci = (int)((unsigned)k / KK);
            int r  = k - ci * KK;
            int dy = (int)((unsigned)r / KS);
            int dx = r - dy * KS;
            int iy  = yB + dy - PAD;
            int iyc = min(max(iy, 0), Hin - 1);
            const float* rp;
            if (ci < C0) rp = s0 + ((size_t)(bB * C0 + ci) * Hin + iyc) * Win;
            else         rp = s1 + ((size_t)(bB * C1 + (ci - C0)) * Hin + iyc) * Win;
            bool rowok = (iy >= 0) && (iy < Hin);
            int xb = x0B + dx - PAD;
            unsigned short* dst = (unsigned short*)&ldsB[grp * 256 + kr];
            #pragma unroll
            for (int px = 0; px < 8; ++px) {
                int ix  = xb + px;
                int ixc = min(max(ix, 0), Win - 1);
                float v = rp[ixc];                 // always in-bounds (clamped)
                bool ok = rowok && (ix >= 0) && (ix < Win);
                dst[px * 32] = f2bf(ok ? v : 0.f);
            }
        }
        __syncthreads();
        // ---- MFMA
        short8 bv = *(const short8*)&ldsB[(wv * 16 + m) * 32 + quad * 8];
        #pragma unroll
        for (int q = 0; q < MB / 16; ++q) {
            short8 av = *(const short8*)&ldsA[(q * 16 + m) * 32 + quad * 8];
            acc[q] = __builtin_amdgcn_mfma_f32_16x16x32_bf16(av, bv, acc[q], 0, 0, 0);
        }
        __syncthreads();
        wA += 32;
    }

    // ---- epilogue: bias + mish, f32 store
    const int Pp = pixbase + wv * 16 + m;
    const int bO = Pp >> lgHW;
    const int pO = Pp & (HW - 1);
    #pragma unroll
    for (int q = 0; q < MB / 16; ++q) {
        #pragma unroll
        for (int r = 0; r < 4; ++r) {
            int co = cobase + q * 16 + quad * 4 + r;
            float v = acc[q][r] + bias[co];
            out[((size_t)(bO * Co + co) << lgHW) + pO] = mishf(v);
        }
    }
}

// ---------------- 2x2 maxpool stride 2 ----------------
__global__ __launch_bounds__(256) void k_maxpool(
        const float* __restrict__ in, float* __restrict__ out,
        int Hin, int Win, int total) {
    int idx = blockIdx.x * 256 + threadIdx.x;
    if (idx >= total) return;
    int Wo = Win >> 1, Ho = Hin >> 1;
    int xo = idx % Wo; int t = idx / Wo;
    int yo = t % Ho;   t /= Ho;
    const float* p = in + ((size_t)t * Hin + 2 * yo) * Win + 2 * xo;
    out[idx] = fmaxf(fmaxf(p[0], p[1]), fmaxf(p[Win], p[Win + 1]));
}

// ---------------- batchnorm (batch stats) ----------------
__global__ __launch_bounds__(256) void k_bn_reduce(
        const float* __restrict__ in, float* __restrict__ stats) {
    __shared__ float ls[4], ls2[4];
    int c = blockIdx.x;
    int tid = threadIdx.x;
    float s = 0.f, s2 = 0.f;
    for (int i = tid; i < 4096; i += 256) {
        int b = i >> 10, r = i & 1023;
        float v = in[((size_t)(b * 512 + c) << 10) + r];
        s += v; s2 += v * v;
    }
    #pragma unroll
    for (int off = 32; off; off >>= 1) {
        s  += __shfl_down(s, off, 64);
        s2 += __shfl_down(s2, off, 64);
    }
    if ((tid & 63) == 0) { ls[tid >> 6] = s; ls2[tid >> 6] = s2; }
    __syncthreads();
    if (tid == 0) {
        s  = ls[0] + ls[1] + ls[2] + ls[3];
        s2 = ls2[0] + ls2[1] + ls2[2] + ls2[3];
        float mean = s * (1.f / 4096.f);
        float var  = fmaxf(s2 * (1.f / 4096.f) - mean * mean, 0.f);
        stats[c]       = mean;
        stats[512 + c] = rsqrtf(var + 1e-5f);
    }
}

__global__ __launch_bounds__(256) void k_bn_apply(
        float* __restrict__ data, const float* __restrict__ stats,
        const float* __restrict__ g, const float* __restrict__ be, int total) {
    int idx = blockIdx.x * 256 + threadIdx.x;
    if (idx >= total) return;
    int c = (idx >> 10) & 511;
    float v = data[idx];
    data[idx] = g[c] * (v - stats[c]) * stats[512 + c] + be[c];
}

// ------------- bilinear x2 upsample, align_corners=True ----------------------
__global__ __launch_bounds__(256) void k_up2b(
        const float* __restrict__ in, float* __restrict__ out,
        int C, int H, int W, int total) {
    int idx = blockIdx.x * 256 + threadIdx.x;
    if (idx >= total) return;
    int Wo = W * 2, Ho = H * 2;
    int xo = idx % Wo; int t = idx / Wo;
    int yo = t % Ho;   int c = t / Ho;
    float scy = (float)(H - 1) / (float)(Ho - 1);
    float scx = (float)(W - 1) / (float)(Wo - 1);
    float sy = yo * scy, sx = xo * scx;
    int y0 = (int)sy; int y1 = min(y0 + 1, H - 1); float fy = sy - (float)y0;
    int x0 = (int)sx; int x1 = min(x0 + 1, W - 1); float fx = sx - (float)x0;
    const float* p = in + (size_t)c * H * W;
    float a  = p[y0 * W + x0] * (1.f - fx) + p[y0 * W + x1] * fx;
    float b2 = p[y1 * W + x0] * (1.f - fx) + p[y1 * W + x1] * fx;
    out[idx] = a * (1.f - fy) + b2 * fy;
}

// ---------------- final 1x1 conv, 32 -> 1, f32 out ----------------
__global__ __launch_bounds__(256) void k_final1x1(
        const float* __restrict__ in, const float* __restrict__ wl,
        const float* __restrict__ bl, float* __restrict__ out) {
    int idx = blockIdx.x * 256 + threadIdx.x;
    if (idx >= 4 * 256 * 256) return;
    int pix = idx & 65535;
    int b = idx >> 16;
    float acc = bl[0];
    #pragma unroll
    for (int ci = 0; ci < 32; ++ci)
        acc = fmaf(in[((size_t)(b * 32 + ci) << 16) + pix], wl[ci], acc);
    out[idx] = acc;
}

static inline int nblk(long long n) { return (int)((n + 255) / 256); }

extern "C" void kernel_launch(void* const* d_in, const int* in_sizes, int n_in,
                              void* d_out, int out_size, void* d_ws, size_t ws_size,
                              hipStream_t stream) {
    static const int EXP_SZ[N_T] = {
        262144, 2048, 16384, 32, 36864, 128, 147456, 128,
        294912, 256, 589824, 256, 1179648, 512, 2359296, 512,
        512, 512, 1769472, 256, 589824, 256, 442368, 128,
        147456, 128, 46080, 32, 9216, 32, 32, 1 };
    static const int ISW[N_T] = {   // 3x3 / k=4 conv weights -> bf16
        0,0,1,0, 1,0,1,0, 1,0,1,0, 1,0,1,0,
        0,0, 1,0,1,0, 1,0,1,0, 1,0,1,0, 0,0 };
    int o = -1;
    for (int s = 0; s + N_T <= n_in; ++s) {
        bool ok = true;
        for (int j = 0; j < N_T; ++j)
            if (in_sizes[s + j] != EXP_SZ[j]) { ok = false; break; }
        if (ok) { o = s; break; }
    }
    if (o < 0) return;

    float* ws = (float*)d_ws;
    // layout (float indices)
    const long long PFN   = 270336;       // f32 params (non-weights): 267,905 used
    const long long C1o   = PFN;
    const long long C2o   = C1o + 8388608;
    const long long C3o   = C2o + 8388608;
    const long long Po    = C3o + 4194304;
    const long long Qo    = Po  + 8388608;
    const long long STo   = Qo  + 8388608;
    const long long FLo   = STo + 1024;
    const long long WBo   = FLo + 64;     // ushort region starts here (float idx)
    const long long WBN   = 7628800;      // bf16 weight elements
    const size_t NEED = (size_t)WBo * 4 + WBN * 2 + 256;
    if (ws_size < NEED) return;

    float* PF = ws;
    float* C1 = ws + C1o;
    float* C2 = ws + C2o;
    float* C3 = ws + C3o;
    float* P  = ws + Po;
    float* Q  = ws + Qo;
    float* ST = ws + STo;
    int* FLAGS = (int*)(ws + FLo);
    unsigned short* WB = (unsigned short*)(ws + WBo);

    Tab tab;
    long long foff = 0, woff = 0, total = 0;
    const float* fp[N_T];
    const unsigned short* wbp[N_T];
    for (int i = 0; i < N_T; ++i) {
        tab.src[i] = d_in[o + i];
        tab.n[i]   = in_sizes[o + i];
        tab.isw[i] = ISW[i];
        if (ISW[i]) { tab.dstoff[i] = woff; wbp[i] = WB + woff; fp[i] = nullptr; woff += tab.n[i]; }
        else        { tab.dstoff[i] = foff; fp[i] = PF + foff; wbp[i] = nullptr; foff += tab.n[i]; }
        total += tab.n[i];
    }
    if (foff > PFN || woff > WBN) return;

    const float* xf  = fp[0];  const float* wf = fp[1];
    const unsigned short* d1w = wbp[2];  const float* d1b = fp[3];
    const unsigned short* w2a = wbp[4];  const float* b2a = fp[5];
    const unsigned short* w2b = wbp[6];  const float* b2b = fp[7];
    const unsigned short* w3a = wbp[8];  const float* b3a = fp[9];
    const unsigned short* w3b = wbp[10]; const float* b3b = fp[11];
    const unsigned short* w4a = wbp[12]; const float* b4a = fp[13];
    const unsigned short* w4b = wbp[14]; const float* b4b = fp[15];
    const float* g4 = fp[16], *be4 = fp[17];
    const unsigned short* u3a = wbp[18]; const float* ub3a = fp[19];
    const unsigned short* u3b = wbp[20]; const float* ub3b = fp[21];
    const unsigned short* u2a = wbp[22]; const float* ub2a = fp[23];
    const unsigned short* u2b = wbp[24]; const float* ub2b = fp[25];
    const unsigned short* u1a = wbp[26]; const float* ub1a = fp[27];
    const unsigned short* u1b = wbp[28]; const float* ub1b = fp[29];
    const float* wl = fp[30], *bl = fp[31];
    float* outp = (float*)d_out;

    dim3 blk(256);
    long long n;

    k_detect<<<N_T, blk, 0, stream>>>(tab, FLAGS);
    k_flag_final<<<1, 64, 0, stream>>>(tab, FLAGS, 0);
    k_convert<<<nblk(total), blk, 0, stream>>>(tab, PF, WB, FLAGS);

    // ---- encoder ----
    n = 4ll * 32 * 255 * 255;
    k_dynconv_mish<<<nblk(n), blk, 0, stream>>>(xf, wf, P);
    // d1: k=4 pad=2, in P (32ch,255x255) -> C1 (4,32,256,256). N=262144
    k_conv_mfma<4, 32><<<dim3(4096, 1), blk, 0, stream>>>(
        P, 32, nullptr, 0, d1w, d1b, C1, 255, 255, 8, 16, 32, 512);
    n = 4ll * 32 * 128 * 128;
    k_maxpool<<<nblk(n), blk, 0, stream>>>(C1, Q, 256, 256, (int)n);
    // c2a: 32->128 @128^2 (N=65536)
    k_conv_mfma<3, 64><<<dim3(1024, 2), blk, 0, stream>>>(
        Q, 32, nullptr, 0, w2a, b2a, P, 128, 128, 7, 14, 128, 288);
    k_conv_mfma<3, 64><<<dim3(1024, 2), blk, 0, stream>>>(
        P, 128, nullptr, 0, w2b, b2b, C2, 128, 128, 7, 14, 128, 1152);
    n = 4ll * 128 * 64 * 64;
    k_maxpool<<<nblk(n), blk, 0, stream>>>(C2, Q, 128, 128, (int)n);
    // c3a: 128->256 @64^2 (N=16384)
    k_conv_mfma<3, 64><<<dim3(256, 4), blk, 0, stream>>>(
        Q, 128, nullptr, 0, w3a, b3a, P, 64, 64, 6, 12, 256, 1152);
    k_conv_mfma<3, 64><<<dim3(256, 4), blk, 0, stream>>>(
        P, 256, nullptr, 0, w3b, b3b, C3, 64, 64, 6, 12, 256, 2304);
    n = 4ll * 256 * 32 * 32;
    k_maxpool<<<nblk(n), blk, 0, stream>>>(C3, Q, 64, 64, (int)n);
    // c4a: 256->512 @32^2 (N=4096)
    k_conv_mfma<3, 64><<<dim3(64, 8), blk, 0, stream>>>(
        Q, 256, nullptr, 0, w4a, b4a, P, 32, 32, 5, 10, 512, 2304);
    k_conv_mfma<3, 64><<<dim3(64, 8), blk, 0, stream>>>(
        P, 512, nullptr, 0, w4b, b4b, Q, 32, 32, 5, 10, 512, 4608);
    n = 4ll * 512 * 32 * 32;
    k_bn_reduce<<<512, blk, 0, stream>>>(Q, ST);
    k_bn_apply<<<nblk(n), blk, 0, stream>>>(Q, ST, g4, be4, (int)n);

    // ---- decoder ----
    // up2 full-batch: Q (4,512,32,32) -> P (4,512,64,64)
    n = 4ll * 512 * 64 * 64;
    k_up2b<<<nblk(n), blk, 0, stream>>>(Q, P, 2048, 32, 32, (int)n);
    // u3a: [P:512 | C3:256] -> Q (4,256,64,64); K = 768*9 = 6912
    k_conv_mfma<3, 64><<<dim3(256, 4), blk, 0, stream>>>(
        P, 512, C3, 256, u3a, ub3a, Q, 64, 64, 6, 12, 256, 6912);
    k_conv_mfma<3, 64><<<dim3(256, 4), blk, 0, stream>>>(
        Q, 256, nullptr, 0, u3b, ub3b, P, 64, 64, 6, 12, 256, 2304);

    // stage 2 per batch: up2(P_b) -> U2(=C3 slot), conv -> Q_b
    float* U2 = C3;
    for (int b = 0; b < 4; ++b) {
        k_up2b<<<nblk(4194304), blk, 0, stream>>>(P + (size_t)b * 1048576, U2,
                                                  256, 64, 64, 4194304);
        k_conv_mfma<3, 64><<<dim3(256, 2), blk, 0, stream>>>(
            U2, 256, C2 + (size_t)b * 2097152, 128, u2a, ub2a,
            Q + (size_t)b * 2097152, 128, 128, 7, 14, 128, 3456);
    }
    // u2b full-batch: Q (4,128,128,128) -> P
    k_conv_mfma<3, 64><<<dim3(1024, 2), blk, 0, stream>>>(
        Q, 128, nullptr, 0, u2b, ub2b, P, 128, 128, 7, 14, 128, 1152);

    // stage 1 per batch: up2(P_b) -> U1(=C2 slot), conv -> Q_b
    float* U1 = C2;
    for (int b = 0; b < 4; ++b) {
        k_up2b<<<nblk(8388608), blk, 0, stream>>>(P + (size_t)b * 2097152, U1,
                                                  128, 128, 128, 8388608);
        k_conv_mfma<3, 32><<<dim3(1024, 1), blk, 0, stream>>>(
            U1, 128, C1 + (size_t)b * 2097152, 32, u1a, ub1a,
            Q + (size_t)b * 2097152, 256, 256, 8, 16, 32, 1440);
    }
    // u1b full-batch: Q (4,32,256,256) -> P
    k_conv_mfma<3, 32><<<dim3(4096, 1), blk, 0, stream>>>(
        Q, 32, nullptr, 0, u1b, ub1b, P, 256, 256, 8, 16, 32, 288);

    // final 1x1 -> f32 out
    n = 4ll * 256 * 256;
    k_final1x1<<<nblk(n), blk, 0, stream>>>(P, wl, bl, outp);
}

// Round 9
// 1747.699 us; speedup vs baseline: 24.8251x; 2.3542x over previous
//
#include <hip/hip_runtime.h>
#include <hip/hip_bf16.h>
#include <math.h>

#define DEV static __device__ __forceinline__

typedef __attribute__((ext_vector_type(8))) short short8;
typedef __attribute__((ext_vector_type(4))) float floatx4;

DEV float bf2f(const __hip_bfloat16 v) { return __bfloat162float(v); }
DEV float bfu2f(unsigned short u) { return __uint_as_float((unsigned)u << 16); }

DEV unsigned short f2bf(float v) {   // RNE f32 -> bf16 bits
    unsigned int b = __float_as_uint(v);
    unsigned int r = (b + 0x7FFFu + ((b >> 16) & 1u)) >> 16;
    return (unsigned short)r;
}

DEV float mishf(float x) {
    float sp = fmaxf(x, 0.0f) + log1pf(expf(-fabsf(x)));
    float t = expf(-2.0f * sp);
    return x * (1.0f - t) / (1.0f + t);
}

#define N_T 32
struct Tab {
    const void* src[N_T];
    long long   dstoff[N_T];
    int         n[N_T];
    int         isw[N_T];   // 1 = conv weight -> bf16 WB region (transposed)
    int         cin[N_T];
    int         kk[N_T];
};

// ---------------- per-array dtype detection ----------------
__global__ __launch_bounds__(256) void k_detect(Tab t, int* __restrict__ flags) {
    int i = blockIdx.x;
    int n = t.n[i];
    int m = n < 16384 ? n : 16384;
    const unsigned short* p = (const unsigned short*)t.src[i];
    __shared__ int sInf, sExt, sZero;
    if (threadIdx.x == 0) { sInf = 0; sExt = 0; sZero = 0; }
    __syncthreads();
    int cInf = 0, cExt = 0, cZero = 0;
    for (int j = threadIdx.x; j < m; j += 256) {
        unsigned short h = p[j];
        if ((h & 0x7F80) == 0x7F80) cInf++;
        if ((j & 1) == 0) {
            if (h == 0) cZero++;
            else { int e = (h >> 7) & 0xFF; if (e < 56 || e > 184) cExt++; }
        }
    }
    if (cInf)  atomicAdd(&sInf, cInf);
    if (cExt)  atomicAdd(&sExt, cExt);
    if (cZero) atomicAdd(&sZero, cZero);
    __syncthreads();
    if (threadIdx.x == 0) {
        int nEven = (m + 1) >> 1;
        flags[i] = (sInf > 0 || sExt > 0 || (nEven > 0 && sZero == nEven)) ? 2 : 0;
    }
}

__global__ void k_flag_final(Tab t, int* __restrict__ flags, int xi) {
    if (threadIdx.x == 0 && blockIdx.x == 0) {
        int xf = (flags[xi] == 2) ? 1 : 0;
        for (int i = 0; i < N_T; ++i) {
            int f;
            if (flags[i] == 2)       f = 1;
            else if (t.n[i] >= 256)  f = 0;
            else                     f = xf;
            flags[i] = f;            // 1 = f32, 0 = bf16
        }
    }
}

// convert: conv weights -> bf16 WB, layout [co][dy][dx][ci]; others -> f32 PF
__global__ __launch_bounds__(256) void k_convert(
        Tab t, float* __restrict__ pf, unsigned short* __restrict__ wb,
        const int* __restrict__ flags) {
    long long idx = (long long)blockIdx.x * 256 + threadIdx.x;
    long long off = 0;
    #pragma unroll 1
    for (int i = 0; i < N_T; ++i) {
        long long ni = t.n[i];
        if (idx < off + ni) {
            int j = (int)(idx - off);
            float v = flags[i] ? ((const float*)t.src[i])[j]
                               : bf2f(((const __hip_bfloat16*)t.src[i])[j]);
            if (t.isw[i]) {
                int cin = t.cin[i], kk = t.kk[i];
                int ckk = cin * kk;
                int co = j / ckk;
                int rem = j - co * ckk;
                int ci = rem / kk;
                int tt = rem - ci * kk;
                wb[t.dstoff[i] + (size_t)co * ckk + tt * cin + ci] = f2bf(v);
            } else {
                pf[t.dstoff[i] + j] = v;
            }
            return;
        }
        off += ni;
    }
}

// ------- dynamic per-sample conv (k=4, pad=1) + mish -> NHWC bf16 -----------
// x: (4,256,256) f32, w: (4,32,4,4) f32, out: (4,255,255,32) bf16
__global__ __launch_bounds__(256) void k_dynconv_mish(
        const float* __restrict__ x, const float* __restrict__ w,
        unsigned short* __restrict__ out) {
    const int HO = 255, WO = 255, H = 256, W = 256;
    int idx = blockIdx.x * 256 + threadIdx.x;
    int total = 4 * HO * WO * 32;
    if (idx >= total) return;
    int co = idx & 31; int t = idx >> 5;
    int xo = t % WO;  t /= WO;
    int yo = t % HO;  int b = t / HO;
    const float* wp = w + (((b << 5) + co) << 4);
    const float* xp = x + b * H * W;
    float acc = 0.0f;
    #pragma unroll
    for (int ky = 0; ky < 4; ++ky) {
        int iy = yo + ky - 1;
        if ((unsigned)iy >= (unsigned)H) continue;
        const float* row = xp + iy * W;
        #pragma unroll
        for (int kx = 0; kx < 4; ++kx) {
            int ix = xo + kx - 1;
            if ((unsigned)ix < (unsigned)W)
                acc = fmaf(row[ix], wp[ky * 4 + kx], acc);
        }
    }
    out[idx] = f2bf(mishf(acc));
}

// ============ NHWC direct-conv MFMA (bf16 in/out, f32 acc) ===================
// A = weights [co][dy][dx][ci] bf16; feature maps NHWC bf16.
// Block: MB co x 64 pixels; K-order (dy,dx,ci) in 32-ci steps.
template<int KS, int MB>
__global__ __launch_bounds__(256) void k_conv_mfma(
        const unsigned short* __restrict__ s0, int C0,
        const unsigned short* __restrict__ s1, int C1,
        const unsigned short* __restrict__ wgt,
        const float* __restrict__ bias,
        unsigned short* __restrict__ out,
        int Hin, int Win, int lgW, int lgHW, int Co) {
    constexpr int PAD = (KS == 3) ? 1 : 2;
    __shared__ __align__(16) unsigned short ldsA[MB * 40];
    __shared__ __align__(16) unsigned short ldsB[64 * 40];
    const int tid = threadIdx.x, lane = tid & 63, wv = tid >> 6;
    const int m = lane & 15, quad = lane >> 4;
    const int W = 1 << lgW, HW = 1 << lgHW;
    const int C = C0 + C1;
    const int Ktot = KS * KS * C;
    const int pixbase = blockIdx.x * 64, cobase = blockIdx.y * MB;

    // B staging: thread -> (pixel pl, 8-ci group)
    const int pl = tid >> 2, ci8 = (tid & 3) * 8;
    const int pxs = pixbase + pl;
    const int bS = pxs >> lgHW, ppS = pxs & (HW - 1);
    const int yS = ppS >> lgW, xS = ppS & (W - 1);

    // A staging: thread -> (co row, 8-k segment)
    const bool aok = (tid >> 2) < MB;
    const int co_r = aok ? (tid >> 2) : (MB - 1);
    const int seg = tid & 3;
    const unsigned short* wA = wgt + (size_t)(cobase + co_r) * Ktot + seg * 8;

    floatx4 acc[MB / 16];
    #pragma unroll
    for (int q = 0; q < MB / 16; ++q) acc[q] = (floatx4){0.f, 0.f, 0.f, 0.f};

    for (int dy = 0; dy < KS; ++dy) {
        int iy = yS + dy - PAD;
        bool yok = (iy >= 0) && (iy < Hin);
        for (int dx = 0; dx < KS; ++dx) {
            int ix = xS + dx - PAD;
            bool ok = yok && (ix >= 0) && (ix < Win);
            long long sb = ((long long)bS * Hin + iy) * Win + ix;
            for (int cs = 0; cs < C; cs += 32) {
                uint4 a4;
                if (aok) a4 = *(const uint4*)wA;
                uint4 b4 = {0u, 0u, 0u, 0u};
                if (ok) {
                    const unsigned short* sp = (cs < C0)
                        ? s0 + (size_t)sb * C0 + cs + ci8
                        : s1 + (size_t)sb * C1 + (cs - C0) + ci8;
                    b4 = *(const uint4*)sp;
                }
                *(uint4*)&ldsB[pl * 40 + ci8] = b4;
                if (aok) *(uint4*)&ldsA[co_r * 40 + seg * 8] = a4;
                __syncthreads();
                short8 bv = *(const short8*)&ldsB[(wv * 16 + m) * 40 + quad * 8];
                #pragma unroll
                for (int q = 0; q < MB / 16; ++q) {
                    short8 av = *(const short8*)&ldsA[(q * 16 + m) * 40 + quad * 8];
                    acc[q] = __builtin_amdgcn_mfma_f32_16x16x32_bf16(av, bv, acc[q], 0, 0, 0);
                }
                __syncthreads();
                wA += 32;
            }
        }
    }
    // epilogue: bias + mish -> NHWC bf16, 4 consecutive co per lane (8B store)
    const int pxo = pixbase + wv * 16 + m;
    const int bO = pxo >> lgHW, pO = pxo & (HW - 1);
    unsigned short* obase = out + ((size_t)bO * HW + pO) * Co;
    #pragma unroll
    for (int q = 0; q < MB / 16; ++q) {
        int co = cobase + q * 16 + quad * 4;
        ushort4 o;
        o.x = f2bf(mishf(acc[q][0] + bias[co + 0]));
        o.y = f2bf(mishf(acc[q][1] + bias[co + 1]));
        o.z = f2bf(mishf(acc[q][2] + bias[co + 2]));
        o.w = f2bf(mishf(acc[q][3] + bias[co + 3]));
        *(ushort4*)(obase + co) = o;
    }
}

// ---------------- 2x2 maxpool stride 2 (NHWC bf16, square pow2) -------------
__global__ __launch_bounds__(256) void k_maxpool(
        const unsigned short* __restrict__ in, unsigned short* __restrict__ out,
        int lgWin, int lgC, int total) {
    int idx = blockIdx.x * 256 + threadIdx.x;
    if (idx >= total) return;
    int C = 1 << lgC, Wo = 1 << (lgWin - 1);
    int c = idx & (C - 1); int t = idx >> lgC;
    int xo = t & (Wo - 1); t >>= (lgWin - 1);
    int yo = t & (Wo - 1); int b = t >> (lgWin - 1);
    size_t base = ((((size_t)(b << lgWin) + 2 * yo) << lgWin) + 2 * xo) << lgC;
    size_t dc = (size_t)1 << lgC, dr = (size_t)1 << (lgWin + lgC);
    float v0 = bfu2f(in[base + c]);
    float v1 = bfu2f(in[base + dc + c]);
    float v2 = bfu2f(in[base + dr + c]);
    float v3 = bfu2f(in[base + dr + dc + c]);
    out[idx] = f2bf(fmaxf(fmaxf(v0, v1), fmaxf(v2, v3)));
}

// ---------------- batchnorm (batch stats) on NHWC (4,32,32,512) bf16 --------
__global__ __launch_bounds__(256) void k_bn_reduce(
        const unsigned short* __restrict__ in, float* __restrict__ stats) {
    __shared__ float ls[4], ls2[4];
    int c = blockIdx.x;
    int tid = threadIdx.x;
    float s = 0.f, s2 = 0.f;
    for (int i = tid; i < 4096; i += 256) {
        float v = bfu2f(in[(size_t)i * 512 + c]);
        s += v; s2 += v * v;
    }
    #pragma unroll
    for (int off = 32; off; off >>= 1) {
        s  += __shfl_down(s, off, 64);
        s2 += __shfl_down(s2, off, 64);
    }
    if ((tid & 63) == 0) { ls[tid >> 6] = s; ls2[tid >> 6] = s2; }
    __syncthreads();
    if (tid == 0) {
        s  = ls[0] + ls[1] + ls[2] + ls[3];
        s2 = ls2[0] + ls2[1] + ls2[2] + ls2[3];
        float mean = s * (1.f / 4096.f);
        float var  = fmaxf(s2 * (1.f / 4096.f) - mean * mean, 0.f);
        stats[c]       = mean;
        stats[512 + c] = rsqrtf(var + 1e-5f);
    }
}

__global__ __launch_bounds__(256) void k_bn_apply(
        unsigned short* __restrict__ data, const float* __restrict__ stats,
        const float* __restrict__ g, const float* __restrict__ be, int total) {
    int idx = blockIdx.x * 256 + threadIdx.x;
    if (idx >= total) return;
    int c = idx & 511;
    float v = bfu2f(data[idx]);
    data[idx] = f2bf(g[c] * (v - stats[c]) * stats[512 + c] + be[c]);
}

// -------- bilinear x2 upsample, align_corners=True, NHWC bf16, square pow2 ---
__global__ __launch_bounds__(256) void k_up2(
        const unsigned short* __restrict__ in, unsigned short* __restrict__ out,
        int lgW, int lgC, int total) {
    int idx = blockIdx.x * 256 + threadIdx.x;
    if (idx >= total) return;
    int H = 1 << lgW, C = 1 << lgC;
    int c = idx & (C - 1); int t = idx >> lgC;
    int xo = t & (2 * H - 1); t >>= (lgW + 1);
    int yo = t & (2 * H - 1); int b = t >> (lgW + 1);
    float sc = (float)(H - 1) / (float)(2 * H - 1);
    float sy = yo * sc, sx = xo * sc;
    int y0 = (int)sy; int y1 = min(y0 + 1, H - 1); float fy = sy - (float)y0;
    int x0 = (int)sx; int x1 = min(x0 + 1, H - 1); float fx = sx - (float)x0;
    size_t bb = (size_t)b << (2 * lgW);
    size_t i00 = (((bb + ((size_t)y0 << lgW) + x0)) << lgC) + c;
    size_t i01 = (((bb + ((size_t)y0 << lgW) + x1)) << lgC) + c;
    size_t i10 = (((bb + ((size_t)y1 << lgW) + x0)) << lgC) + c;
    size_t i11 = (((bb + ((size_t)y1 << lgW) + x1)) << lgC) + c;
    float a  = bfu2f(in[i00]) * (1.f - fx) + bfu2f(in[i01]) * fx;
    float b2 = bfu2f(in[i10]) * (1.f - fx) + bfu2f(in[i11]) * fx;
    out[idx] = f2bf(a * (1.f - fy) + b2 * fy);
}

// ---------------- final 1x1 conv, NHWC(4,256,256,32) bf16 -> f32 ------------
__global__ __launch_bounds__(256) void k_final1x1(
        const unsigned short* __restrict__ in, const float* __restrict__ wl,
        const float* __restrict__ bl, float* __restrict__ out) {
    int idx = blockIdx.x * 256 + threadIdx.x;
    if (idx >= 4 * 256 * 256) return;
    const unsigned short* p = in + (size_t)idx * 32;
    float acc = bl[0];
    #pragma unroll
    for (int ci = 0; ci < 32; ++ci)
        acc = fmaf(bfu2f(p[ci]), wl[ci], acc);
    out[idx] = acc;
}

static inline int nblk(long long n) { return (int)((n + 255) / 256); }

extern "C" void kernel_launch(void* const* d_in, const int* in_sizes, int n_in,
                              void* d_out, int out_size, void* d_ws, size_t ws_size,
                              hipStream_t stream) {
    static const int EXP_SZ[N_T] = {
        262144, 2048, 16384, 32, 36864, 128, 147456, 128,
        294912, 256, 589824, 256, 1179648, 512, 2359296, 512,
        512, 512, 1769472, 256, 589824, 256, 442368, 128,
        147456, 128, 46080, 32, 9216, 32, 32, 1 };
    static const int ISW[N_T] = {
        0,0,1,0, 1,0,1,0, 1,0,1,0, 1,0,1,0,
        0,0, 1,0,1,0, 1,0,1,0, 1,0,1,0, 0,0 };
    static const int CIN[N_T] = {
        0,0,32,0, 32,0,128,0, 128,0,256,0, 256,0,512,0,
        0,0, 768,0,256,0, 384,0,128,0, 160,0,32,0, 0,0 };
    static const int KKA[N_T] = {
        0,0,16,0, 9,0,9,0, 9,0,9,0, 9,0,9,0,
        0,0, 9,0,9,0, 9,0,9,0, 9,0,9,0, 0,0 };
    int o = -1;
    for (int s = 0; s + N_T <= n_in; ++s) {
        bool ok = true;
        for (int j = 0; j < N_T; ++j)
            if (in_sizes[s + j] != EXP_SZ[j]) { ok = false; break; }
        if (ok) { o = s; break; }
    }
    if (o < 0) return;

    float* ws = (float*)d_ws;
    const long long PFN   = 270336;
    const long long C1o   = PFN;
    const long long C2o   = C1o + 8388608;
    const long long C3o   = C2o + 8388608;
    const long long Po    = C3o + 4194304;
    const long long Qo    = Po  + 8388608;
    const long long STo   = Qo  + 8388608;
    const long long FLo   = STo + 1024;
    const long long WBo   = FLo + 64;
    const long long WBN   = 7628800;
    const size_t NEED = (size_t)WBo * 4 + WBN * 2 + 256;
    if (ws_size < NEED) return;

    float* PF = ws;
    unsigned short* C1 = (unsigned short*)(ws + C1o);
    unsigned short* C2 = (unsigned short*)(ws + C2o);
    unsigned short* C3 = (unsigned short*)(ws + C3o);
    unsigned short* P  = (unsigned short*)(ws + Po);
    unsigned short* Q  = (unsigned short*)(ws + Qo);
    float* ST = ws + STo;
    int* FLAGS = (int*)(ws + FLo);
    unsigned short* WB = (unsigned short*)(ws + WBo);

    Tab tab;
    long long foff = 0, woff = 0, total = 0;
    const float* fp[N_T];
    const unsigned short* wbp[N_T];
    for (int i = 0; i < N_T; ++i) {
        tab.src[i] = d_in[o + i];
        tab.n[i]   = in_sizes[o + i];
        tab.isw[i] = ISW[i];
        tab.cin[i] = CIN[i];
        tab.kk[i]  = KKA[i];
        if (ISW[i]) { tab.dstoff[i] = woff; wbp[i] = WB + woff; fp[i] = nullptr; woff += tab.n[i]; }
        else        { tab.dstoff[i] = foff; fp[i] = PF + foff; wbp[i] = nullptr; foff += tab.n[i]; }
        total += tab.n[i];
    }
    if (foff > PFN || woff > WBN) return;

    const float* xf  = fp[0];  const float* wf = fp[1];
    const unsigned short* d1w = wbp[2];  const float* d1b = fp[3];
    const unsigned short* w2a = wbp[4];  const float* b2a = fp[5];
    const unsigned short* w2b = wbp[6];  const float* b2b = fp[7];
    const unsigned short* w3a = wbp[8];  const float* b3a = fp[9];
    const unsigned short* w3b = wbp[10]; const float* b3b = fp[11];
    const unsigned short* w4a = wbp[12]; const float* b4a = fp[13];
    const unsigned short* w4b = wbp[14]; const float* b4b = fp[15];
    const float* g4 = fp[16], *be4 = fp[17];
    const unsigned short* u3aw = wbp[18]; const float* ub3a = fp[19];
    const unsigned short* u3bw = wbp[20]; const float* ub3b = fp[21];
    const unsigned short* u2aw = wbp[22]; const float* ub2a = fp[23];
    const unsigned short* u2bw = wbp[24]; const float* ub2b = fp[25];
    const unsigned short* u1aw = wbp[26]; const float* ub1a = fp[27];
    const unsigned short* u1bw = wbp[28]; const float* ub1b = fp[29];
    const float* wl = fp[30], *bl = fp[31];
    float* outp = (float*)d_out;

    dim3 blk(256);
    long long n;

    k_detect<<<N_T, blk, 0, stream>>>(tab, FLAGS);
    k_flag_final<<<1, 64, 0, stream>>>(tab, FLAGS, 0);
    k_convert<<<nblk(total), blk, 0, stream>>>(tab, PF, WB, FLAGS);

    // ---- encoder (NHWC bf16 feature maps) ----
    n = 4ll * 255 * 255 * 32;
    k_dynconv_mish<<<nblk(n), blk, 0, stream>>>(xf, wf, P);
    // d1: k=4 pad=2, in P (4,255,255,32) -> C1 (4,256,256,32)
    k_conv_mfma<4, 32><<<dim3(4096, 1), blk, 0, stream>>>(
        P, 32, nullptr, 0, d1w, d1b, C1, 255, 255, 8, 16, 32);
    n = 4ll * 128 * 128 * 32;
    k_maxpool<<<nblk(n), blk, 0, stream>>>(C1, Q, 8, 5, (int)n);
    // c2a: 32->128 @128^2
    k_conv_mfma<3, 64><<<dim3(1024, 2), blk, 0, stream>>>(
        Q, 32, nullptr, 0, w2a, b2a, P, 128, 128, 7, 14, 128);
    k_conv_mfma<3, 64><<<dim3(1024, 2), blk, 0, stream>>>(
        P, 128, nullptr, 0, w2b, b2b, C2, 128, 128, 7, 14, 128);
    n = 4ll * 64 * 64 * 128;
    k_maxpool<<<nblk(n), blk, 0, stream>>>(C2, Q, 7, 7, (int)n);
    // c3a: 128->256 @64^2
    k_conv_mfma<3, 64><<<dim3(256, 4), blk, 0, stream>>>(
        Q, 128, nullptr, 0, w3a, b3a, P, 64, 64, 6, 12, 256);
    k_conv_mfma<3, 64><<<dim3(256, 4), blk, 0, stream>>>(
        P, 256, nullptr, 0, w3b, b3b, C3, 64, 64, 6, 12, 256);
    n = 4ll * 32 * 32 * 256;
    k_maxpool<<<nblk(n), blk, 0, stream>>>(C3, Q, 6, 8, (int)n);
    // c4a: 256->512 @32^2
    k_conv_mfma<3, 64><<<dim3(64, 8), blk, 0, stream>>>(
        Q, 256, nullptr, 0, w4a, b4a, P, 32, 32, 5, 10, 512);
    k_conv_mfma<3, 64><<<dim3(64, 8), blk, 0, stream>>>(
        P, 512, nullptr, 0, w4b, b4b, Q, 32, 32, 5, 10, 512);
    n = 4ll * 32 * 32 * 512;
    k_bn_reduce<<<512, blk, 0, stream>>>(Q, ST);
    k_bn_apply<<<nblk(n), blk, 0, stream>>>(Q, ST, g4, be4, (int)n);

    // ---- decoder ----
    // stage 3: up2 Q (4,32,32,512) -> P (4,64,64,512)
    n = 4ll * 64 * 64 * 512;
    k_up2<<<nblk(n), blk, 0, stream>>>(Q, P, 5, 9, (int)n);
    // u3a: [P:512 | C3:256] -> Q (4,64,64,256)
    k_conv_mfma<3, 64><<<dim3(256, 4), blk, 0, stream>>>(
        P, 512, C3, 256, u3aw, ub3a, Q, 64, 64, 6, 12, 256);
    k_conv_mfma<3, 64><<<dim3(256, 4), blk, 0, stream>>>(
        Q, 256, nullptr, 0, u3bw, ub3b, P, 64, 64, 6, 12, 256);

    // stage 2 per batch: up2(P_b (64,64,256)) -> U2(=C3 region), conv -> Q_b
    unsigned short* U2 = C3;
    for (int b = 0; b < 4; ++b) {
        k_up2<<<nblk(4194304), blk, 0, stream>>>(P + (size_t)b * 1048576, U2,
                                                 6, 8, 4194304);
        k_conv_mfma<3, 64><<<dim3(256, 2), blk, 0, stream>>>(
            U2, 256, C2 + (size_t)b * 2097152, 128, u2aw, ub2a,
            Q + (size_t)b * 2097152, 128, 128, 7, 14, 128);
    }
    // u2b: Q (4,128,128,128) -> P
    k_conv_mfma<3, 64><<<dim3(1024, 2), blk, 0, stream>>>(
        Q, 128, nullptr, 0, u2bw, ub2b, P, 128, 128, 7, 14, 128);

    // stage 1 per batch: up2(P_b (128,128,128)) -> U1(=C2 region), conv -> Q_b
    unsigned short* U1 = C2;
    for (int b = 0; b < 4; ++b) {
        k_up2<<<nblk(8388608), blk, 0, stream>>>(P + (size_t)b * 2097152, U1,
                                                 7, 7, 8388608);
        k_conv_mfma<3, 32><<<dim3(1024, 1), blk, 0, stream>>>(
            U1, 128, C1 + (size_t)b * 2097152, 32, u1aw, ub1a,
            Q + (size_t)b * 2097152, 256, 256, 8, 16, 32);
    }
    // u1b: Q (4,256,256,32) -> P
    k_conv_mfma<3, 32><<<dim3(4096, 1), blk, 0, stream>>>(
        Q, 32, nullptr, 0, u1bw, ub1b, P, 256, 256, 8, 16, 32);

    // final 1x1 -> f32 out (NCHW == NHW for 1 channel)
    n = 4ll * 256 * 256;
    k_final1x1<<<nblk(n), blk, 0, stream>>>(P, wl, bl, outp);
}